// Round 17
// baseline (465.896 us; speedup 1.0000x reference)
//
#include <hip/hip_runtime.h>

#define NN 50000
#define NE 400000
#define CAP 64    // per-node in-edge bucket capacity (P(deg>64) ~ 1e-45 at E/N=8)
#define PACKN (7*16384 + 32768 + 32768)   // 180224: 7x128^2 + W1 + W2
#define PACKN2 (PACKN + 32768)            // + pWeg (combined We|Wg, 16 tiles)
#define PACKB ((PACKN2 + 255)/256)        // 832 pack blocks

typedef unsigned int u32;
typedef unsigned short u16;
typedef __attribute__((ext_vector_type(8))) short short8; // 8 bf16 = 4 VGPR
typedef __attribute__((ext_vector_type(4))) float f32x4;
typedef __attribute__((ext_vector_type(4))) unsigned int u32x4;

union FragU { uint4 u; short8 s; };
union Chunk { uint4 v[4]; u32 d[16]; };

__device__ __forceinline__ float bflo(u32 w){ union{u32 i; float f;} v; v.i = w<<16; return v.f; }
__device__ __forceinline__ float bfhi(u32 w){ union{u32 i; float f;} v; v.i = w & 0xffff0000u; return v.f; }
__device__ __forceinline__ u32 packbf(float a, float b){
  union{float f;u32 i;} x, y; x.f=a; y.f=b;
  u32 xi = x.i + (((x.i>>16)&1u) + 0x7fffu);
  u32 yi = y.i + (((y.i>>16)&1u) + 0x7fffu);
  return (xi>>16) | (yi & 0xffff0000u);
}

// Raw barrier: LDS visibility only (lgkmcnt). Global loads/stores STAY IN FLIGHT.
#define BAR() do { \
  asm volatile("s_waitcnt lgkmcnt(0)" ::: "memory"); \
  __builtin_amdgcn_s_barrier(); \
  asm volatile("" ::: "memory"); \
} while(0)

// swizzled dword index in a [rows][128]-bf16 tile (64 u32/row)
__device__ __forceinline__ int swz64(int row, int cp){ return row*64 + (cp ^ ((row&7)<<2)); }

// Stage 64 rows with LayerNorm -> bf16 swizzled tile. 4 threads/row (256-thread blocks).
__device__ __forceinline__ void stage_ln(const float* __restrict__ src, long base, long nrows,
                                         const float* __restrict__ gam, const float* __restrict__ bet,
                                         u32* __restrict__ tile, int t)
{
  int row = t>>2, sub = t&3;
  bool valid = (base + row) < nrows;
  const float* p = src + (base+row)*128 + sub*32;
  float4 x[8];
  float s=0.f, s2=0.f;
  #pragma unroll
  for(int q=0;q<8;++q){
    x[q] = valid ? *(const float4*)(p + 4*q) : make_float4(0.f,0.f,0.f,0.f);
    s  += x[q].x + x[q].y + x[q].z + x[q].w;
    s2 += x[q].x*x[q].x + x[q].y*x[q].y + x[q].z*x[q].z + x[q].w*x[q].w;
  }
  s  += __shfl_xor(s,1);  s  += __shfl_xor(s,2);
  s2 += __shfl_xor(s2,1); s2 += __shfl_xor(s2,2);
  float mu  = s*(1.f/128.f);
  float var = fmaxf(s2*(1.f/128.f) - mu*mu, 0.f);
  float rs  = rsqrtf(var + 1e-5f);
  const float* gp = gam + sub*32; const float* bp = bet + sub*32;
  #pragma unroll
  for(int m4=0;m4<4;++m4){
    float4 g0 = *(const float4*)(gp + 8*m4);
    float4 g1 = *(const float4*)(gp + 8*m4 + 4);
    float4 b0 = *(const float4*)(bp + 8*m4);
    float4 b1 = *(const float4*)(bp + 8*m4 + 4);
    float4 xa = x[2*m4], xb = x[2*m4+1];
    uint4 wv;
    wv.x = packbf((xa.x-mu)*rs*g0.x+b0.x, (xa.y-mu)*rs*g0.y+b0.y);
    wv.y = packbf((xa.z-mu)*rs*g0.z+b0.z, (xa.w-mu)*rs*g0.w+b0.w);
    wv.z = packbf((xb.x-mu)*rs*g1.x+b1.x, (xb.y-mu)*rs*g1.y+b1.y);
    wv.w = packbf((xb.z-mu)*rs*g1.z+b1.z, (xb.w-mu)*rs*g1.w+b1.w);
    *(uint4*)&tile[swz64(row, sub*16 + m4*4)] = wv;
  }
}

// Stage variant for 512-thread blocks: 8 threads/row, no bounds check (NE % 64 == 0).
__device__ __forceinline__ void stage_ln8(const float* __restrict__ src, long base,
                                          const float* __restrict__ gam, const float* __restrict__ bet,
                                          u32* __restrict__ tile, int t)
{
  int row = t>>3, sub = t&7;
  const float* p = src + (base+row)*128 + sub*16;
  float4 x[4];
  float s=0.f, s2=0.f;
  #pragma unroll
  for(int q=0;q<4;++q){
    x[q] = *(const float4*)(p + 4*q);
    s  += x[q].x + x[q].y + x[q].z + x[q].w;
    s2 += x[q].x*x[q].x + x[q].y*x[q].y + x[q].z*x[q].z + x[q].w*x[q].w;
  }
  s  += __shfl_xor(s,1);  s  += __shfl_xor(s,2);  s  += __shfl_xor(s,4);
  s2 += __shfl_xor(s2,1); s2 += __shfl_xor(s2,2); s2 += __shfl_xor(s2,4);
  float mu  = s*(1.f/128.f);
  float var = fmaxf(s2*(1.f/128.f) - mu*mu, 0.f);
  float rs  = rsqrtf(var + 1e-5f);
  const float* gp = gam + sub*16; const float* bp = bet + sub*16;
  #pragma unroll
  for(int m4=0;m4<2;++m4){
    float4 g0 = *(const float4*)(gp + 8*m4);
    float4 g1 = *(const float4*)(gp + 8*m4 + 4);
    float4 b0 = *(const float4*)(bp + 8*m4);
    float4 b1 = *(const float4*)(bp + 8*m4 + 4);
    float4 xa = x[2*m4], xb = x[2*m4+1];
    uint4 wv;
    wv.x = packbf((xa.x-mu)*rs*g0.x+b0.x, (xa.y-mu)*rs*g0.y+b0.y);
    wv.y = packbf((xa.z-mu)*rs*g0.z+b0.z, (xa.w-mu)*rs*g0.w+b0.w);
    wv.z = packbf((xb.x-mu)*rs*g1.x+b1.x, (xb.y-mu)*rs*g1.y+b1.y);
    wv.w = packbf((xb.z-mu)*rs*g1.z+b1.z, (xb.w-mu)*rs*g1.w+b1.w);
    *(uint4*)&tile[swz64(row, sub*8 + m4*4)] = wv;
  }
}

// D^T = W^T x data; 8 mt tiles, K=128.
__device__ __forceinline__ void gemmT8(const u16* __restrict__ PW, int NT, int mtoff,
                                       const u32* __restrict__ tile, int row, int l,
                                       f32x4 acc[8])
{
  int g = l>>4;
  #pragma unroll
  for(int kc=0;kc<4;++kc){
    FragU bf; bf.u = *(const uint4*)&tile[swz64(row, kc*16 + g*4)];
    #pragma unroll
    for(int mt=0;mt<8;++mt){
      FragU af; af.u = ((const uint4*)PW)[(size_t)(kc*NT + mtoff + mt)*64 + l];
      acc[mt] = __builtin_amdgcn_mfma_f32_16x16x32_bf16(af.s, bf.s, acc[mt], 0,0,0);
    }
  }
}

// 4-mt variant (wave owns 4 column tiles).
__device__ __forceinline__ void gemmT4(const u16* __restrict__ PW, int NT, int mtoff,
                                       const u32* __restrict__ tile, int row, int l,
                                       f32x4 acc[4])
{
  int g = l>>4;
  #pragma unroll
  for(int kc=0;kc<4;++kc){
    FragU bf; bf.u = *(const uint4*)&tile[swz64(row, kc*16 + g*4)];
    #pragma unroll
    for(int m=0;m<4;++m){
      FragU af; af.u = ((const uint4*)PW)[(size_t)(kc*NT + mtoff + m)*64 + l];
      acc[m] = __builtin_amdgcn_mfma_f32_16x16x32_bf16(af.s, bf.s, acc[m], 0,0,0);
    }
  }
}

// ---------------- K0: pack weights (blocks 0..PACKB-1) + bucket-scatter (rest) ------
__global__ __launch_bounds__(256)
void k_prep(const float* __restrict__ Wq, const float* __restrict__ Wk,
            const float* __restrict__ Wv, const float* __restrict__ We,
            const float* __restrict__ Wg, const float* __restrict__ Woe,
            const float* __restrict__ Wo, const float* __restrict__ W1,
            const float* __restrict__ W2, u16* __restrict__ dst,
            const int* __restrict__ eidx, int* __restrict__ cnt, int* __restrict__ elist)
{
  if (blockIdx.x < PACKB){
    int i = blockIdx.x*256 + threadIdx.x;
    const float* src; int N, idx, nt_override = -1;
    if (i < 7*16384){
      int m = i >> 14; idx = i & 16383; N=128;
      src = (m==0)?Wq:(m==1)?Wk:(m==2)?Wv:(m==3)?We:(m==4)?Wg:(m==5)?Woe:Wo;
    } else if (i < 7*16384 + 32768){ idx = i - 7*16384; N=256; src = W1; }
    else if (i < PACKN){ idx = i - 7*16384 - 32768; N=128; src = W2; }
    else if (i < PACKN2){
      idx = i - PACKN; N=128;
      int rest = idx >> 9;
      int T = rest & 15;
      int half = T>>3, within = T&7;
      nt_override = half*4 + (within&3);
      src = (within>>2) ? Wg : We;
    }
    else return;
    int j = idx & 7, l = (idx>>3) & 63;
    int rest = idx >> 9;
    int NT = (nt_override >= 0) ? 16 : (N >> 4);
    int nt = (nt_override >= 0) ? nt_override : (rest % NT);
    int kc = rest / NT;
    int k = kc*32 + (l>>4)*8 + j;
    int n = nt*16 + (l&15);
    union{float f;u32 u;} x; x.f = src[(size_t)k*N + n];
    dst[i] = (u16)((x.u + (((x.u>>16)&1u) + 0x7fffu)) >> 16);
  } else {
    int e = (blockIdx.x - PACKB)*256 + threadIdx.x;
    if (e < NE){
      int d = eidx[NE+e];
      int pos = atomicAdd(&cnt[d], 1);
      if (pos < CAP) elist[(size_t)d*CAP + pos] = e;
    }
  }
}

// ---------------- K1: node LN + q,k,v projections ----------------
// PERMUTED rows: dword (g*16 + mt*2 + j2) holds feats mt*16+g*4+2*j2 {lo,hi}.
__global__ __launch_bounds__(256)
void k_qkv(const float* __restrict__ xin,
           const float* __restrict__ l1g, const float* __restrict__ l1b,
           const u16* __restrict__ pWq, const float* __restrict__ bq,
           const u16* __restrict__ pWk, const float* __restrict__ bk,
           const u16* __restrict__ pWv, const float* __restrict__ bv,
           u32* __restrict__ qv, u32* __restrict__ kv, u32* __restrict__ vv)
{
  __shared__ u32 tile[64*64];
  int t = threadIdx.x;
  long base = (long)blockIdx.x * 64;
  stage_ln(xin, base, NN, l1g, l1b, tile, t);
  BAR();
  int w = t>>6, l = t&63, g = l>>4;
  int row = w*16 + (l&15);
  long node = base + row;
  bool valid = node < NN;

  f32x4 acc[8];
  const u16* pws[3] = {pWq, pWk, pWv};
  const float* bbs[3] = {bq, bk, bv};
  u32* outs[3] = {qv, kv, vv};
  #pragma unroll
  for(int s3=0;s3<3;++s3){
    #pragma unroll
    for(int mt=0;mt<8;++mt) acc[mt] = (f32x4){0.f,0.f,0.f,0.f};
    gemmT8(pws[s3], 8, 0, tile, row, l, acc);
    if (valid){
      Chunk c;
      #pragma unroll
      for(int mt=0;mt<8;++mt){
        float4 bb = *(const float4*)(bbs[s3] + mt*16 + g*4);
        c.d[mt*2]   = packbf(acc[mt][0]+bb.x, acc[mt][1]+bb.y);
        c.d[mt*2+1] = packbf(acc[mt][2]+bb.z, acc[mt][3]+bb.w);
      }
      uint4* op = (uint4*)(outs[s3] + node*64 + g*16);
      #pragma unroll
      for(int i=0;i<4;++i) op[i] = c.v[i];
    }
  }
}

// ---------------- K2: fused edge pass, merged We|Wg GEMM, 2 raw barriers ------------
__global__ __launch_bounds__(512)
void k_edge(const float* __restrict__ ein,
            const float* __restrict__ l1eg, const float* __restrict__ l1eb,
            const u16* __restrict__ pWeg, const float* __restrict__ bg,
            const float* __restrict__ be,
            const u16* __restrict__ pWoe, const float* __restrict__ boe,
            const int* __restrict__ eidx,
            const u32* __restrict__ qv, const u32* __restrict__ kv, const u32* __restrict__ vv,
            u32* __restrict__ gvp, float* __restrict__ escp,
            float* __restrict__ eout)
{
  __shared__ u32 tile[64*64];
  __shared__ u32 stile[64*64];   // s_elt tile (separate: no WAR barrier needed)
  int t = threadIdx.x;
  long base = (long)blockIdx.x * 64;
  stage_ln8(ein, base, l1eg, l1eb, tile, t);

  int w = t>>6, l = t&63, g = l>>4;
  int rg = w&3, half = w>>2;            // wave = (row-group of 16, mt-half)
  int row = rg*16 + (l&15);
  long edge = base + row;
  int s_ = eidx[edge], d_ = eidx[NE + edge];
  BAR();                                // stage LDS visible; global ops stay in flight

  // all global reads issued up front; they fly under the merged GEMM
  float4 er[4];
  #pragma unroll
  for(int m=0;m<4;++m)
    er[m] = *(const float4*)(ein + edge*128 + (half*4+m)*16 + g*4);
  const uint4* qp = (const uint4*)(qv + (size_t)d_*64 + g*16 + half*8);
  const uint4* kp = (const uint4*)(kv + (size_t)s_*64 + g*16 + half*8);
  const uint4* vp = (const uint4*)(vv + (size_t)s_*64 + g*16 + half*8);
  uint4 qa = qp[0], qb = qp[1];
  uint4 ka = kp[0], kb = kp[1];
  uint4 va = vp[0], vb = vp[1];
  uint2 qw[4] = {{qa.x,qa.y},{qa.z,qa.w},{qb.x,qb.y},{qb.z,qb.w}};
  uint2 kw[4] = {{ka.x,ka.y},{ka.z,ka.w},{kb.x,kb.y},{kb.z,kb.w}};
  uint2 vw[4] = {{va.x,va.y},{va.z,va.w},{vb.x,vb.y},{vb.z,vb.w}};

  // merged GEMM: acc8[0..3] = LN(e)@We (this half), acc8[4..7] = LN(e)@Wg
  f32x4 acc8[8];
  #pragma unroll
  for(int m=0;m<8;++m) acc8[m] = (f32x4){0.f,0.f,0.f,0.f};
  gemmT8(pWeg, 16, half*8, tile, row, l, acc8);

  // s_elt = We-part + be + q*k; scores -> esc; s_elt -> stile immediately
  float esc4[4];
  #pragma unroll
  for(int m=0;m<4;++m){
    int mt = half*4 + m;
    float4 bb = *(const float4*)(be + mt*16 + g*4);
    acc8[m][0] += bb.x + bflo(qw[m].x)*bflo(kw[m].x);
    acc8[m][1] += bb.y + bfhi(qw[m].x)*bfhi(kw[m].x);
    acc8[m][2] += bb.z + bflo(qw[m].y)*bflo(kw[m].y);
    acc8[m][3] += bb.w + bfhi(qw[m].y)*bfhi(kw[m].y);
    uint2 o;
    o.x = packbf(acc8[m][0], acc8[m][1]);
    o.y = packbf(acc8[m][2], acc8[m][3]);
    *(uint2*)&stile[swz64(row, mt*8 + g*2)] = o;
    float ps = acc8[m][0]+acc8[m][1]+acc8[m][2]+acc8[m][3];
    ps += __shfl_xor(ps, 16);
    ps += __shfl_xor(ps, 32);                 // sum over all 16 feats of head mt
    float sc = fminf(fmaxf(ps*0.25f, -5.f), 5.f);
    esc4[m] = __expf(sc);                     // clipped => no max-subtract needed
  }
  if (g==0){
    float4 e0 = {esc4[0],esc4[1],esc4[2],esc4[3]};
    *(float4*)(escp + (size_t)edge*8 + half*4) = e0;   // normal store (L2 merges)
  }
  // gate = sigmoid(Wg-part + bg); gv = gate (x) v[src]
  // gv layout: dword (half*32 + g*8 + m*2 + j2) -> wave writes full 128B per edge
  {
    u32 gd[8];
    #pragma unroll
    for(int m=0;m<4;++m){
      int mt = half*4 + m;
      float4 bb = *(const float4*)(bg + mt*16 + g*4);
      float g0 = 1.f/(1.f+__expf(-(acc8[4+m][0]+bb.x)));
      float g1 = 1.f/(1.f+__expf(-(acc8[4+m][1]+bb.y)));
      float g2 = 1.f/(1.f+__expf(-(acc8[4+m][2]+bb.z)));
      float g3 = 1.f/(1.f+__expf(-(acc8[4+m][3]+bb.w)));
      gd[m*2]   = packbf(g0*bflo(vw[m].x), g1*bfhi(vw[m].x));
      gd[m*2+1] = packbf(g2*bflo(vw[m].y), g3*bfhi(vw[m].y));
    }
    u32x4* gp2 = (u32x4*)(gvp + (size_t)edge*64 + half*32 + g*8);
    u32x4 g0v = {gd[0],gd[1],gd[2],gd[3]};
    u32x4 g1v = {gd[4],gd[5],gd[6],gd[7]};
    __builtin_nontemporal_store(g0v, gp2);
    __builtin_nontemporal_store(g1v, gp2+1);
  }
  BAR();                         // stile visible (single barrier for the whole tail)
  // e_out = e_in + s_elt@Woe + boe   (residual er already in regs; NT store, full lines)
  f32x4 oac[4];
  #pragma unroll
  for(int m=0;m<4;++m) oac[m] = (f32x4){0.f,0.f,0.f,0.f};
  gemmT4(pWoe, 8, half*4, stile, row, l, oac);
  #pragma unroll
  for(int m=0;m<4;++m){
    int mt = half*4 + m;
    float4 bb = *(const float4*)(boe + mt*16 + g*4);
    f32x4 o;
    o[0] = er[m].x + oac[m][0] + bb.x;
    o[1] = er[m].y + oac[m][1] + bb.y;
    o[2] = er[m].z + oac[m][2] + bb.z;
    o[3] = er[m].w + oac[m][3] + bb.w;
    __builtin_nontemporal_store(o, (f32x4*)(eout + edge*128 + mt*16 + g*4));
  }
}

// ---------------- K3: fused aggregation + node epilogue ----------------
// Phase 0: per-node CSR walk -> normalized attn out written DIRECTLY into LDS tile.
// gv dword l: half=l>>5, g=(l>>3)&3, m=(l>>1)&3, j2=l&1; head h=half*4+m;
// tile column cp=(half*4+m)*8+g*2+j2 (inverse of the gv permutation).
__global__ __launch_bounds__(256)
void k_out(const float* __restrict__ xin,
           const u32* __restrict__ gvp, const float* __restrict__ escp,
           const int* __restrict__ elist, const int* __restrict__ cnt,
           const u16* __restrict__ pWo, const float* __restrict__ bo,
           const float* __restrict__ l2g, const float* __restrict__ l2b,
           const u16* __restrict__ pW1, const float* __restrict__ b1p,
           const u16* __restrict__ pW2, const float* __restrict__ b2p,
           float* __restrict__ xout)
{
  __shared__ u32 tile[64*64];
  __shared__ u32 hhalf[64*64];
  int t = threadIdx.x;
  long base = (long)blockIdx.x * 64;
  int w = t>>6, l = t&63, g = l>>4;
  // ---- phase 0: aggregation walk (wave w handles rows w*16..w*16+15) ----
  {
    int half2 = l>>5, gg2 = (l>>3)&3, m2 = (l>>1)&3, j2 = l&1;
    int h  = half2*4 + m2;
    int cp = (half2*4 + m2)*8 + gg2*2 + j2;
    for (int i=0;i<16;++i){
      int rrow = w*16 + i;
      long node = base + rrow;
      float s0=0.f, s1=0.f, den=0.f;
      if (node < NN){
        int e = min(cnt[node], CAP);
        const int* el = elist + (size_t)node*CAP;
        int ii = 0;
        for (; ii+8<=e; ii+=8){
          int ed[8];
          #pragma unroll
          for(int j=0;j<8;++j) ed[j] = el[ii+j];
          u32 gw[8]; float a[8];
          #pragma unroll
          for(int j=0;j<8;++j){ gw[j] = gvp[(size_t)ed[j]*64 + l]; a[j] = escp[(size_t)ed[j]*8 + h]; }
          #pragma unroll
          for(int j=0;j<8;++j){ s0 += a[j]*bflo(gw[j]); s1 += a[j]*bfhi(gw[j]); den += a[j]; }
        }
        if (ii < e){
          int mm = e - ii;  // 1..7
          int ed[7]; u32 gw[7]; float a[7];
          #pragma unroll
          for(int j=0;j<7;++j) if (j < mm) ed[j] = el[ii+j];
          #pragma unroll
          for(int j=0;j<7;++j) if (j < mm){ gw[j] = gvp[(size_t)ed[j]*64 + l]; a[j] = escp[(size_t)ed[j]*8 + h]; }
          #pragma unroll
          for(int j=0;j<7;++j) if (j < mm){ s0 += a[j]*bflo(gw[j]); s1 += a[j]*bfhi(gw[j]); den += a[j]; }
        }
      }
      float inv = den>0.f ? 1.f/den : 0.f;  // zero in-degree -> 0 (segment_sum semantics)
      tile[swz64(rrow, cp)] = packbf(s0*inv, s1*inv);
    }
  }
  BAR();
  int row = w*16 + (l&15);
  long node = base + row;
  bool valid = node < NN;

  // xin residual issued early; consumed after Wo GEMM
  float4 xr[8];
  #pragma unroll
  for(int mt=0;mt<8;++mt)
    xr[mt] = valid ? *(const float4*)(xin + node*128 + mt*16 + g*4) : make_float4(0.f,0.f,0.f,0.f);

  // Wo GEMM; xmid = x_in + out@Wo + bo
  f32x4 acc[8], xm[8];
  #pragma unroll
  for(int mt=0;mt<8;++mt) acc[mt] = (f32x4){0.f,0.f,0.f,0.f};
  gemmT8(pWo, 8, 0, tile, row, l, acc);
  #pragma unroll
  for(int mt=0;mt<8;++mt){
    float4 bb = *(const float4*)(bo + mt*16 + g*4);
    xm[mt][0] = xr[mt].x + acc[mt][0] + bb.x;
    xm[mt][1] = xr[mt].y + acc[mt][1] + bb.y;
    xm[mt][2] = xr[mt].z + acc[mt][2] + bb.z;
    xm[mt][3] = xr[mt].w + acc[mt][3] + bb.w;
  }
  // LN2 in-register
  float s=0.f, s2=0.f;
  #pragma unroll
  for(int mt=0;mt<8;++mt){
    s  += xm[mt][0]+xm[mt][1]+xm[mt][2]+xm[mt][3];
    s2 += xm[mt][0]*xm[mt][0]+xm[mt][1]*xm[mt][1]+xm[mt][2]*xm[mt][2]+xm[mt][3]*xm[mt][3];
  }
  s  += __shfl_xor(s,16);  s  += __shfl_xor(s,32);
  s2 += __shfl_xor(s2,16); s2 += __shfl_xor(s2,32);
  float mu  = s*(1.f/128.f);
  float var = fmaxf(s2*(1.f/128.f) - mu*mu, 0.f);
  float rs  = rsqrtf(var + 1e-5f);
  BAR();                        // done reading tile (Wo B-frags)
  #pragma unroll
  for(int mt=0;mt<8;++mt){
    float4 gg = *(const float4*)(l2g + mt*16 + g*4);
    float4 bb = *(const float4*)(l2b + mt*16 + g*4);
    float h0 = (xm[mt][0]-mu)*rs*gg.x + bb.x;
    float h1 = (xm[mt][1]-mu)*rs*gg.y + bb.y;
    float h2 = (xm[mt][2]-mu)*rs*gg.z + bb.z;
    float h3 = (xm[mt][3]-mu)*rs*gg.w + bb.w;
    uint2 o; o.x = packbf(h0,h1); o.y = packbf(h2,h3);
    *(uint2*)&tile[swz64(row, mt*8 + g*2)] = o;
  }
  BAR();
  // FFN: per 128-col half, compute h-half -> hhalf, accumulate FFN2 (K=128 chunk)
  f32x4 oacc[8];
  #pragma unroll
  for(int mt=0;mt<8;++mt) oacc[mt] = (f32x4){0.f,0.f,0.f,0.f};
  #pragma unroll
  for(int hf=0; hf<2; ++hf){
    f32x4 dh[8];
    #pragma unroll
    for(int mt=0;mt<8;++mt) dh[mt] = (f32x4){0.f,0.f,0.f,0.f};
    gemmT8(pW1, 16, hf*8, tile, row, l, dh);
    #pragma unroll
    for(int mt=0;mt<8;++mt){
      int feat = hf*128 + mt*16 + g*4;
      float4 bb = *(const float4*)(b1p + feat);
      float h0 = fmaxf(dh[mt][0]+bb.x, 0.f);
      float h1 = fmaxf(dh[mt][1]+bb.y, 0.f);
      float h2 = fmaxf(dh[mt][2]+bb.z, 0.f);
      float h3 = fmaxf(dh[mt][3]+bb.w, 0.f);
      uint2 o; o.x = packbf(h0,h1); o.y = packbf(h2,h3);
      *(uint2*)&hhalf[swz64(row, mt*8 + g*2)] = o;
    }
    BAR();
    gemmT8(pW2 + (size_t)hf*16384, 8, 0, hhalf, row, l, oacc);
    BAR();                      // before next half overwrites hhalf
  }
  if (valid){
    #pragma unroll
    for(int mt=0;mt<8;++mt){
      float4 bb = *(const float4*)(b2p + mt*16 + g*4);
      f32x4 o;
      o[0] = xm[mt][0] + oacc[mt][0] + bb.x;
      o[1] = xm[mt][1] + oacc[mt][1] + bb.y;
      o[2] = xm[mt][2] + oacc[mt][2] + bb.z;
      o[3] = xm[mt][3] + oacc[mt][3] + bb.w;
      __builtin_nontemporal_store(o, (f32x4*)(xout + node*128 + mt*16 + g*4));
    }
  }
}

extern "C" void kernel_launch(void* const* d_in, const int* in_sizes, int n_in,
                              void* d_out, int out_size, void* d_ws, size_t ws_size,
                              hipStream_t stream) {
  (void)in_sizes; (void)n_in; (void)out_size; (void)ws_size;
  const float* xin = (const float*)d_in[0];
  const float* ein = (const float*)d_in[1];
  const float* Wq = (const float*)d_in[2];  const float* bq = (const float*)d_in[3];
  const float* Wk = (const float*)d_in[4];  const float* bk = (const float*)d_in[5];
  const float* Wv = (const float*)d_in[6];  const float* bv = (const float*)d_in[7];
  const float* We = (const float*)d_in[8];  const float* be = (const float*)d_in[9];
  const float* Wg = (const float*)d_in[10]; const float* bg = (const float*)d_in[11];
  const float* Wo = (const float*)d_in[12]; const float* bo = (const float*)d_in[13];
  const float* Woe= (const float*)d_in[14]; const float* boe= (const float*)d_in[15];
  const float* l1g= (const float*)d_in[16]; const float* l1b= (const float*)d_in[17];
  const float* l1eg=(const float*)d_in[18]; const float* l1eb=(const float*)d_in[19];
  const float* l2g= (const float*)d_in[20]; const float* l2b= (const float*)d_in[21];
  const float* W1 = (const float*)d_in[22]; const float* b1 = (const float*)d_in[23];
  const float* W2 = (const float*)d_in[24]; const float* b2 = (const float*)d_in[25];
  const int* eidx = (const int*)d_in[26];

  float* xout = (float*)d_out;
  float* eout = xout + (size_t)NN*128;

  // ws: esc [NE*8 f32] | gv [NE*64 u32] | qv,kv,vv [NN*64 u32]
  //     | cnt [NN] | elist [NN*CAP] | packed W (bf16)
  float* escp = (float*)d_ws;
  u32* gvp = (u32*)(escp + (size_t)NE*8);
  u32* qv = gvp + (size_t)NE*64;
  u32* kv = qv + (size_t)NN*64;
  u32* vv = kv + (size_t)NN*64;
  int* cnt = (int*)(vv + (size_t)NN*64);
  int* elist = cnt + NN;
  u16* pw  = (u16*)(elist + (size_t)NN*CAP);
  u16* pWq = pw;            u16* pWk = pWq + 16384;  u16* pWv = pWk + 16384;
  u16* pWe = pWv + 16384;   u16* pWg = pWe + 16384;  u16* pWoe= pWg + 16384;
  u16* pWo = pWoe + 16384;  u16* pW1 = pWo + 16384;  u16* pW2 = pW1 + 32768;
  u16* pWeg = pW2 + 32768;
  (void)pWe; (void)pWg;

  hipMemsetAsync(cnt, 0, NN*sizeof(int), stream);
  k_prep<<<PACKB + (NE+255)/256, 256, 0, stream>>>(Wq,Wk,Wv,We,Wg,Woe,Wo,W1,W2, pw,
                                                   eidx, cnt, elist);

  k_qkv<<<(NN+63)/64, 256, 0, stream>>>(xin, l1g, l1b, pWq, bq, pWk, bk, pWv, bv, qv, kv, vv);
  k_edge<<<NE/64, 512, 0, stream>>>(ein, l1eg, l1eb, pWeg, bg, be, pWoe, boe,
                                    eidx, qv, kv, vv, gvp, escp, eout);
  k_out<<<(NN+63)/64, 256, 0, stream>>>(xin, gvp, escp, elist, cnt, pWo, bo, l2g, l2b,
                                        pW1, b1, pW2, b2, xout);
}

// Round 18
// 409.415 us; speedup vs baseline: 1.1380x; 1.1380x over previous
//
#include <hip/hip_runtime.h>

#define NN 50000
#define NE 400000
#define CAP 64    // per-node in-edge bucket capacity (P(deg>64) ~ 1e-45 at E/N=8)
#define PACKN (7*16384 + 32768 + 32768)   // 180224: 7x128^2 + W1 + W2
#define PACKN2 (PACKN + 32768)            // + pWeg (combined We|Wg, 16 tiles)
#define PACKB ((PACKN2 + 255)/256)        // 832 pack blocks

typedef unsigned int u32;
typedef unsigned short u16;
typedef __attribute__((ext_vector_type(8))) short short8; // 8 bf16 = 4 VGPR
typedef __attribute__((ext_vector_type(4))) float f32x4;
typedef __attribute__((ext_vector_type(4))) unsigned int u32x4;

union FragU { uint4 u; short8 s; };
union Chunk { uint4 v[4]; u32 d[16]; };

__device__ __forceinline__ float bflo(u32 w){ union{u32 i; float f;} v; v.i = w<<16; return v.f; }
__device__ __forceinline__ float bfhi(u32 w){ union{u32 i; float f;} v; v.i = w & 0xffff0000u; return v.f; }
__device__ __forceinline__ u32 packbf(float a, float b){
  union{float f;u32 i;} x, y; x.f=a; y.f=b;
  u32 xi = x.i + (((x.i>>16)&1u) + 0x7fffu);
  u32 yi = y.i + (((y.i>>16)&1u) + 0x7fffu);
  return (xi>>16) | (yi & 0xffff0000u);
}

// Raw barrier: LDS visibility only (lgkmcnt). Global loads/stores STAY IN FLIGHT.
#define BAR() do { \
  asm volatile("s_waitcnt lgkmcnt(0)" ::: "memory"); \
  __builtin_amdgcn_s_barrier(); \
  asm volatile("" ::: "memory"); \
} while(0)

// swizzled dword index in a [rows][128]-bf16 tile (64 u32/row)
__device__ __forceinline__ int swz64(int row, int cp){ return row*64 + (cp ^ ((row&7)<<2)); }

// Stage 64 rows with LayerNorm -> bf16 swizzled tile. 4 threads/row (256-thread blocks).
__device__ __forceinline__ void stage_ln(const float* __restrict__ src, long base, long nrows,
                                         const float* __restrict__ gam, const float* __restrict__ bet,
                                         u32* __restrict__ tile, int t)
{
  int row = t>>2, sub = t&3;
  bool valid = (base + row) < nrows;
  const float* p = src + (base+row)*128 + sub*32;
  float4 x[8];
  float s=0.f, s2=0.f;
  #pragma unroll
  for(int q=0;q<8;++q){
    x[q] = valid ? *(const float4*)(p + 4*q) : make_float4(0.f,0.f,0.f,0.f);
    s  += x[q].x + x[q].y + x[q].z + x[q].w;
    s2 += x[q].x*x[q].x + x[q].y*x[q].y + x[q].z*x[q].z + x[q].w*x[q].w;
  }
  s  += __shfl_xor(s,1);  s  += __shfl_xor(s,2);
  s2 += __shfl_xor(s2,1); s2 += __shfl_xor(s2,2);
  float mu  = s*(1.f/128.f);
  float var = fmaxf(s2*(1.f/128.f) - mu*mu, 0.f);
  float rs  = rsqrtf(var + 1e-5f);
  const float* gp = gam + sub*32; const float* bp = bet + sub*32;
  #pragma unroll
  for(int m4=0;m4<4;++m4){
    float4 g0 = *(const float4*)(gp + 8*m4);
    float4 g1 = *(const float4*)(gp + 8*m4 + 4);
    float4 b0 = *(const float4*)(bp + 8*m4);
    float4 b1 = *(const float4*)(bp + 8*m4 + 4);
    float4 xa = x[2*m4], xb = x[2*m4+1];
    uint4 wv;
    wv.x = packbf((xa.x-mu)*rs*g0.x+b0.x, (xa.y-mu)*rs*g0.y+b0.y);
    wv.y = packbf((xa.z-mu)*rs*g0.z+b0.z, (xa.w-mu)*rs*g0.w+b0.w);
    wv.z = packbf((xb.x-mu)*rs*g1.x+b1.x, (xb.y-mu)*rs*g1.y+b1.y);
    wv.w = packbf((xb.z-mu)*rs*g1.z+b1.z, (xb.w-mu)*rs*g1.w+b1.w);
    *(uint4*)&tile[swz64(row, sub*16 + m4*4)] = wv;
  }
}

// Stage variant for 512-thread blocks: 8 threads/row, no bounds check (NE % 64 == 0).
__device__ __forceinline__ void stage_ln8(const float* __restrict__ src, long base,
                                          const float* __restrict__ gam, const float* __restrict__ bet,
                                          u32* __restrict__ tile, int t)
{
  int row = t>>3, sub = t&7;
  const float* p = src + (base+row)*128 + sub*16;
  float4 x[4];
  float s=0.f, s2=0.f;
  #pragma unroll
  for(int q=0;q<4;++q){
    x[q] = *(const float4*)(p + 4*q);
    s  += x[q].x + x[q].y + x[q].z + x[q].w;
    s2 += x[q].x*x[q].x + x[q].y*x[q].y + x[q].z*x[q].z + x[q].w*x[q].w;
  }
  s  += __shfl_xor(s,1);  s  += __shfl_xor(s,2);  s  += __shfl_xor(s,4);
  s2 += __shfl_xor(s2,1); s2 += __shfl_xor(s2,2); s2 += __shfl_xor(s2,4);
  float mu  = s*(1.f/128.f);
  float var = fmaxf(s2*(1.f/128.f) - mu*mu, 0.f);
  float rs  = rsqrtf(var + 1e-5f);
  const float* gp = gam + sub*16; const float* bp = bet + sub*16;
  #pragma unroll
  for(int m4=0;m4<2;++m4){
    float4 g0 = *(const float4*)(gp + 8*m4);
    float4 g1 = *(const float4*)(gp + 8*m4 + 4);
    float4 b0 = *(const float4*)(bp + 8*m4);
    float4 b1 = *(const float4*)(bp + 8*m4 + 4);
    float4 xa = x[2*m4], xb = x[2*m4+1];
    uint4 wv;
    wv.x = packbf((xa.x-mu)*rs*g0.x+b0.x, (xa.y-mu)*rs*g0.y+b0.y);
    wv.y = packbf((xa.z-mu)*rs*g0.z+b0.z, (xa.w-mu)*rs*g0.w+b0.w);
    wv.z = packbf((xb.x-mu)*rs*g1.x+b1.x, (xb.y-mu)*rs*g1.y+b1.y);
    wv.w = packbf((xb.z-mu)*rs*g1.z+b1.z, (xb.w-mu)*rs*g1.w+b1.w);
    *(uint4*)&tile[swz64(row, sub*8 + m4*4)] = wv;
  }
}

// D^T = W^T x data; 8 mt tiles, K=128.
__device__ __forceinline__ void gemmT8(const u16* __restrict__ PW, int NT, int mtoff,
                                       const u32* __restrict__ tile, int row, int l,
                                       f32x4 acc[8])
{
  int g = l>>4;
  #pragma unroll
  for(int kc=0;kc<4;++kc){
    FragU bf; bf.u = *(const uint4*)&tile[swz64(row, kc*16 + g*4)];
    #pragma unroll
    for(int mt=0;mt<8;++mt){
      FragU af; af.u = ((const uint4*)PW)[(size_t)(kc*NT + mtoff + mt)*64 + l];
      acc[mt] = __builtin_amdgcn_mfma_f32_16x16x32_bf16(af.s, bf.s, acc[mt], 0,0,0);
    }
  }
}

// 4-mt variant (wave owns 4 column tiles).
__device__ __forceinline__ void gemmT4(const u16* __restrict__ PW, int NT, int mtoff,
                                       const u32* __restrict__ tile, int row, int l,
                                       f32x4 acc[4])
{
  int g = l>>4;
  #pragma unroll
  for(int kc=0;kc<4;++kc){
    FragU bf; bf.u = *(const uint4*)&tile[swz64(row, kc*16 + g*4)];
    #pragma unroll
    for(int m=0;m<4;++m){
      FragU af; af.u = ((const uint4*)PW)[(size_t)(kc*NT + mtoff + m)*64 + l];
      acc[m] = __builtin_amdgcn_mfma_f32_16x16x32_bf16(af.s, bf.s, acc[m], 0,0,0);
    }
  }
}

// ---------------- K0: pack weights (blocks 0..PACKB-1) + bucket-scatter (rest) ------
__global__ __launch_bounds__(256)
void k_prep(const float* __restrict__ Wq, const float* __restrict__ Wk,
            const float* __restrict__ Wv, const float* __restrict__ We,
            const float* __restrict__ Wg, const float* __restrict__ Woe,
            const float* __restrict__ Wo, const float* __restrict__ W1,
            const float* __restrict__ W2, u16* __restrict__ dst,
            const int* __restrict__ eidx, int* __restrict__ cnt, int* __restrict__ elist)
{
  if (blockIdx.x < PACKB){
    int i = blockIdx.x*256 + threadIdx.x;
    const float* src; int N, idx, nt_override = -1;
    if (i < 7*16384){
      int m = i >> 14; idx = i & 16383; N=128;
      src = (m==0)?Wq:(m==1)?Wk:(m==2)?Wv:(m==3)?We:(m==4)?Wg:(m==5)?Woe:Wo;
    } else if (i < 7*16384 + 32768){ idx = i - 7*16384; N=256; src = W1; }
    else if (i < PACKN){ idx = i - 7*16384 - 32768; N=128; src = W2; }
    else if (i < PACKN2){
      idx = i - PACKN; N=128;
      int rest = idx >> 9;
      int T = rest & 15;
      int half = T>>3, within = T&7;
      nt_override = half*4 + (within&3);
      src = (within>>2) ? Wg : We;
    }
    else return;
    int j = idx & 7, l = (idx>>3) & 63;
    int rest = idx >> 9;
    int NT = (nt_override >= 0) ? 16 : (N >> 4);
    int nt = (nt_override >= 0) ? nt_override : (rest % NT);
    int kc = rest / NT;
    int k = kc*32 + (l>>4)*8 + j;
    int n = nt*16 + (l&15);
    union{float f;u32 u;} x; x.f = src[(size_t)k*N + n];
    dst[i] = (u16)((x.u + (((x.u>>16)&1u) + 0x7fffu)) >> 16);
  } else {
    int e = (blockIdx.x - PACKB)*256 + threadIdx.x;
    if (e < NE){
      int d = eidx[NE+e];
      int pos = atomicAdd(&cnt[d], 1);
      if (pos < CAP) elist[(size_t)d*CAP + pos] = e;
    }
  }
}

// ---------------- K1: node LN + q,k,v projections ----------------
// PERMUTED rows: dword (g*16 + mt*2 + j2) holds feats mt*16+g*4+2*j2 {lo,hi}.
__global__ __launch_bounds__(256)
void k_qkv(const float* __restrict__ xin,
           const float* __restrict__ l1g, const float* __restrict__ l1b,
           const u16* __restrict__ pWq, const float* __restrict__ bq,
           const u16* __restrict__ pWk, const float* __restrict__ bk,
           const u16* __restrict__ pWv, const float* __restrict__ bv,
           u32* __restrict__ qv, u32* __restrict__ kv, u32* __restrict__ vv)
{
  __shared__ u32 tile[64*64];
  int t = threadIdx.x;
  long base = (long)blockIdx.x * 64;
  stage_ln(xin, base, NN, l1g, l1b, tile, t);
  BAR();
  int w = t>>6, l = t&63, g = l>>4;
  int row = w*16 + (l&15);
  long node = base + row;
  bool valid = node < NN;

  f32x4 acc[8];
  const u16* pws[3] = {pWq, pWk, pWv};
  const float* bbs[3] = {bq, bk, bv};
  u32* outs[3] = {qv, kv, vv};
  #pragma unroll
  for(int s3=0;s3<3;++s3){
    #pragma unroll
    for(int mt=0;mt<8;++mt) acc[mt] = (f32x4){0.f,0.f,0.f,0.f};
    gemmT8(pws[s3], 8, 0, tile, row, l, acc);
    if (valid){
      Chunk c;
      #pragma unroll
      for(int mt=0;mt<8;++mt){
        float4 bb = *(const float4*)(bbs[s3] + mt*16 + g*4);
        c.d[mt*2]   = packbf(acc[mt][0]+bb.x, acc[mt][1]+bb.y);
        c.d[mt*2+1] = packbf(acc[mt][2]+bb.z, acc[mt][3]+bb.w);
      }
      uint4* op = (uint4*)(outs[s3] + node*64 + g*16);
      #pragma unroll
      for(int i=0;i<4;++i) op[i] = c.v[i];
    }
  }
}

// ---------------- K2: fused edge pass, merged We|Wg GEMM, 2 raw barriers ------------
__global__ __launch_bounds__(512)
void k_edge(const float* __restrict__ ein,
            const float* __restrict__ l1eg, const float* __restrict__ l1eb,
            const u16* __restrict__ pWeg, const float* __restrict__ bg,
            const float* __restrict__ be,
            const u16* __restrict__ pWoe, const float* __restrict__ boe,
            const int* __restrict__ eidx,
            const u32* __restrict__ qv, const u32* __restrict__ kv, const u32* __restrict__ vv,
            u32* __restrict__ gvp, float* __restrict__ escp,
            float* __restrict__ eout)
{
  __shared__ u32 tile[64*64];
  __shared__ u32 stile[64*64];   // s_elt tile (separate: no WAR barrier needed)
  int t = threadIdx.x;
  long base = (long)blockIdx.x * 64;
  stage_ln8(ein, base, l1eg, l1eb, tile, t);

  int w = t>>6, l = t&63, g = l>>4;
  int rg = w&3, half = w>>2;            // wave = (row-group of 16, mt-half)
  int row = rg*16 + (l&15);
  long edge = base + row;
  int s_ = eidx[edge], d_ = eidx[NE + edge];
  BAR();                                // stage LDS visible; global ops stay in flight

  // all global reads issued up front; they fly under the merged GEMM
  float4 er[4];
  #pragma unroll
  for(int m=0;m<4;++m)
    er[m] = *(const float4*)(ein + edge*128 + (half*4+m)*16 + g*4);
  const uint4* qp = (const uint4*)(qv + (size_t)d_*64 + g*16 + half*8);
  const uint4* kp = (const uint4*)(kv + (size_t)s_*64 + g*16 + half*8);
  const uint4* vp = (const uint4*)(vv + (size_t)s_*64 + g*16 + half*8);
  uint4 qa = qp[0], qb = qp[1];
  uint4 ka = kp[0], kb = kp[1];
  uint4 va = vp[0], vb = vp[1];
  uint2 qw[4] = {{qa.x,qa.y},{qa.z,qa.w},{qb.x,qb.y},{qb.z,qb.w}};
  uint2 kw[4] = {{ka.x,ka.y},{ka.z,ka.w},{kb.x,kb.y},{kb.z,kb.w}};
  uint2 vw[4] = {{va.x,va.y},{va.z,va.w},{vb.x,vb.y},{vb.z,vb.w}};

  // merged GEMM: acc8[0..3] = LN(e)@We (this half), acc8[4..7] = LN(e)@Wg
  f32x4 acc8[8];
  #pragma unroll
  for(int m=0;m<8;++m) acc8[m] = (f32x4){0.f,0.f,0.f,0.f};
  gemmT8(pWeg, 16, half*8, tile, row, l, acc8);

  // s_elt = We-part + be + q*k; scores -> esc; s_elt -> stile immediately
  float esc4[4];
  #pragma unroll
  for(int m=0;m<4;++m){
    int mt = half*4 + m;
    float4 bb = *(const float4*)(be + mt*16 + g*4);
    acc8[m][0] += bb.x + bflo(qw[m].x)*bflo(kw[m].x);
    acc8[m][1] += bb.y + bfhi(qw[m].x)*bfhi(kw[m].x);
    acc8[m][2] += bb.z + bflo(qw[m].y)*bflo(kw[m].y);
    acc8[m][3] += bb.w + bfhi(qw[m].y)*bfhi(kw[m].y);
    uint2 o;
    o.x = packbf(acc8[m][0], acc8[m][1]);
    o.y = packbf(acc8[m][2], acc8[m][3]);
    *(uint2*)&stile[swz64(row, mt*8 + g*2)] = o;
    float ps = acc8[m][0]+acc8[m][1]+acc8[m][2]+acc8[m][3];
    ps += __shfl_xor(ps, 16);
    ps += __shfl_xor(ps, 32);                 // sum over all 16 feats of head mt
    float sc = fminf(fmaxf(ps*0.25f, -5.f), 5.f);
    esc4[m] = __expf(sc);                     // clipped => no max-subtract needed
  }
  if (g==0){
    float4 e0 = {esc4[0],esc4[1],esc4[2],esc4[3]};
    *(float4*)(escp + (size_t)edge*8 + half*4) = e0;   // normal store (L2 merges)
  }
  // gate = sigmoid(Wg-part + bg); gv = gate (x) v[src]
  // gv layout: dword (half*32 + g*8 + m*2 + j2) -> wave writes full 128B per edge
  {
    u32 gd[8];
    #pragma unroll
    for(int m=0;m<4;++m){
      int mt = half*4 + m;
      float4 bb = *(const float4*)(bg + mt*16 + g*4);
      float g0 = 1.f/(1.f+__expf(-(acc8[4+m][0]+bb.x)));
      float g1 = 1.f/(1.f+__expf(-(acc8[4+m][1]+bb.y)));
      float g2 = 1.f/(1.f+__expf(-(acc8[4+m][2]+bb.z)));
      float g3 = 1.f/(1.f+__expf(-(acc8[4+m][3]+bb.w)));
      gd[m*2]   = packbf(g0*bflo(vw[m].x), g1*bfhi(vw[m].x));
      gd[m*2+1] = packbf(g2*bflo(vw[m].y), g3*bfhi(vw[m].y));
    }
    u32x4* gp2 = (u32x4*)(gvp + (size_t)edge*64 + half*32 + g*8);
    u32x4 g0v = {gd[0],gd[1],gd[2],gd[3]};
    u32x4 g1v = {gd[4],gd[5],gd[6],gd[7]};
    __builtin_nontemporal_store(g0v, gp2);
    __builtin_nontemporal_store(g1v, gp2+1);
  }
  BAR();                         // stile visible (single barrier for the whole tail)
  // e_out = e_in + s_elt@Woe + boe   (residual er already in regs; NT store, full lines)
  f32x4 oac[4];
  #pragma unroll
  for(int m=0;m<4;++m) oac[m] = (f32x4){0.f,0.f,0.f,0.f};
  gemmT4(pWoe, 8, half*4, stile, row, l, oac);
  #pragma unroll
  for(int m=0;m<4;++m){
    int mt = half*4 + m;
    float4 bb = *(const float4*)(boe + mt*16 + g*4);
    f32x4 o;
    o[0] = er[m].x + oac[m][0] + bb.x;
    o[1] = er[m].y + oac[m][1] + bb.y;
    o[2] = er[m].z + oac[m][2] + bb.z;
    o[3] = er[m].w + oac[m][3] + bb.w;
    __builtin_nontemporal_store(o, (f32x4*)(eout + edge*128 + mt*16 + g*4));
  }
}

// ---------------- K2b: per-node aggregation over bucketed elist --------------------
// gv layout: dword l covers head mt = (l>>5)*4 + ((l>>1)&3). Output xattnb same layout.
__global__ __launch_bounds__(256)
void k_agg(const u32* __restrict__ gvp, const float* __restrict__ escp,
           const int* __restrict__ elist, const int* __restrict__ cnt,
           u32* __restrict__ xattnb)
{
  int w = threadIdx.x>>6, l = threadIdx.x&63;
  long n = (long)blockIdx.x*4 + w;
  if (n >= NN) return;
  int h = ((l>>5)<<2) | ((l>>1)&3);   // head for this gv dword
  int e = min(cnt[n], CAP);
  const int* el = elist + (size_t)n*CAP;
  float s0=0.f, s1=0.f, den=0.f;
  int i = 0;
  for (; i+8<=e; i+=8){
    int ed[8];
    #pragma unroll
    for(int j=0;j<8;++j) ed[j] = el[i+j];
    u32 gw[8]; float a[8];
    #pragma unroll
    for(int j=0;j<8;++j){ gw[j] = gvp[(size_t)ed[j]*64 + l]; a[j] = escp[(size_t)ed[j]*8 + h]; }
    #pragma unroll
    for(int j=0;j<8;++j){ s0 += a[j]*bflo(gw[j]); s1 += a[j]*bfhi(gw[j]); den += a[j]; }
  }
  if (i < e){
    int m = e - i;  // 1..7
    int ed[7]; u32 gw[7]; float a[7];
    #pragma unroll
    for(int j=0;j<7;++j) if (j < m) ed[j] = el[i+j];
    #pragma unroll
    for(int j=0;j<7;++j) if (j < m){ gw[j] = gvp[(size_t)ed[j]*64 + l]; a[j] = escp[(size_t)ed[j]*8 + h]; }
    #pragma unroll
    for(int j=0;j<7;++j) if (j < m){ s0 += a[j]*bflo(gw[j]); s1 += a[j]*bfhi(gw[j]); den += a[j]; }
  }
  float inv = den>0.f ? 1.f/den : 0.f;  // zero in-degree -> 0 (segment_sum semantics)
  xattnb[n*64 + l] = packbf(s0*inv, s1*inv);
}

// ---------------- K3: node epilogue: Wo, LN2, FFN (32KB LDS, raw barriers) ----------
__global__ __launch_bounds__(256)
void k_out(const float* __restrict__ xin,
           const u32* __restrict__ xattnb,
           const u16* __restrict__ pWo, const float* __restrict__ bo,
           const float* __restrict__ l2g, const float* __restrict__ l2b,
           const u16* __restrict__ pW1, const float* __restrict__ b1p,
           const u16* __restrict__ pW2, const float* __restrict__ b2p,
           float* __restrict__ xout)
{
  __shared__ u32 tile[64*64];
  __shared__ u32 hhalf[64*64];
  int t = threadIdx.x;
  long base = (long)blockIdx.x * 64;
  // stage attention output (xattnb in gv layout) -> swizzled tile
  // dword d = half*32 + g*8 + m*2 + j2  ->  tile cp = (half*4+m)*8 + g*2 + j2
  {
    int row = t>>2, sub = t&3;
    long node = base + row;
    bool valid = node < NN;
    Chunk c;
    if (valid){
      const uint4* p = (const uint4*)(xattnb + node*64 + sub*16);
      #pragma unroll
      for(int i=0;i<4;++i) c.v[i] = p[i];
    } else {
      #pragma unroll
      for(int i=0;i<16;++i) c.d[i] = 0;
    }
    int half = sub>>1;
    #pragma unroll
    for(int p=0;p<8;++p){
      int g = (sub&1)*2 + (p>>2);
      int m = p&3;
      int cp = (half*4 + m)*8 + g*2;
      uint2 o; o.x = c.d[2*p]; o.y = c.d[2*p+1];
      *(uint2*)&tile[swz64(row, cp)] = o;
    }
  }
  BAR();
  int w = t>>6, l = t&63, g = l>>4;
  int row = w*16 + (l&15);
  long node = base + row;
  bool valid = node < NN;

  // xin residual issued early; consumed after Wo GEMM
  float4 xr[8];
  #pragma unroll
  for(int mt=0;mt<8;++mt)
    xr[mt] = valid ? *(const float4*)(xin + node*128 + mt*16 + g*4) : make_float4(0.f,0.f,0.f,0.f);

  // Wo GEMM; xmid = x_in + out@Wo + bo
  f32x4 acc[8], xm[8];
  #pragma unroll
  for(int mt=0;mt<8;++mt) acc[mt] = (f32x4){0.f,0.f,0.f,0.f};
  gemmT8(pWo, 8, 0, tile, row, l, acc);
  #pragma unroll
  for(int mt=0;mt<8;++mt){
    float4 bb = *(const float4*)(bo + mt*16 + g*4);
    xm[mt][0] = xr[mt].x + acc[mt][0] + bb.x;
    xm[mt][1] = xr[mt].y + acc[mt][1] + bb.y;
    xm[mt][2] = xr[mt].z + acc[mt][2] + bb.z;
    xm[mt][3] = xr[mt].w + acc[mt][3] + bb.w;
  }
  // LN2 in-register
  float s=0.f, s2=0.f;
  #pragma unroll
  for(int mt=0;mt<8;++mt){
    s  += xm[mt][0]+xm[mt][1]+xm[mt][2]+xm[mt][3];
    s2 += xm[mt][0]*xm[mt][0]+xm[mt][1]*xm[mt][1]+xm[mt][2]*xm[mt][2]+xm[mt][3]*xm[mt][3];
  }
  s  += __shfl_xor(s,16);  s  += __shfl_xor(s,32);
  s2 += __shfl_xor(s2,16); s2 += __shfl_xor(s2,32);
  float mu  = s*(1.f/128.f);
  float var = fmaxf(s2*(1.f/128.f) - mu*mu, 0.f);
  float rs  = rsqrtf(var + 1e-5f);
  BAR();                        // done reading tile (Wo B-frags)
  #pragma unroll
  for(int mt=0;mt<8;++mt){
    float4 gg = *(const float4*)(l2g + mt*16 + g*4);
    float4 bb = *(const float4*)(l2b + mt*16 + g*4);
    float h0 = (xm[mt][0]-mu)*rs*gg.x + bb.x;
    float h1 = (xm[mt][1]-mu)*rs*gg.y + bb.y;
    float h2 = (xm[mt][2]-mu)*rs*gg.z + bb.z;
    float h3 = (xm[mt][3]-mu)*rs*gg.w + bb.w;
    uint2 o; o.x = packbf(h0,h1); o.y = packbf(h2,h3);
    *(uint2*)&tile[swz64(row, mt*8 + g*2)] = o;
  }
  BAR();
  // FFN: per 128-col half, compute h-half -> hhalf, accumulate FFN2 (K=128 chunk)
  f32x4 oacc[8];
  #pragma unroll
  for(int mt=0;mt<8;++mt) oacc[mt] = (f32x4){0.f,0.f,0.f,0.f};
  #pragma unroll
  for(int hf=0; hf<2; ++hf){
    f32x4 dh[8];
    #pragma unroll
    for(int mt=0;mt<8;++mt) dh[mt] = (f32x4){0.f,0.f,0.f,0.f};
    gemmT8(pW1, 16, hf*8, tile, row, l, dh);
    #pragma unroll
    for(int mt=0;mt<8;++mt){
      int feat = hf*128 + mt*16 + g*4;
      float4 bb = *(const float4*)(b1p + feat);
      float h0 = fmaxf(dh[mt][0]+bb.x, 0.f);
      float h1 = fmaxf(dh[mt][1]+bb.y, 0.f);
      float h2 = fmaxf(dh[mt][2]+bb.z, 0.f);
      float h3 = fmaxf(dh[mt][3]+bb.w, 0.f);
      uint2 o; o.x = packbf(h0,h1); o.y = packbf(h2,h3);
      *(uint2*)&hhalf[swz64(row, mt*8 + g*2)] = o;
    }
    BAR();
    gemmT8(pW2 + (size_t)hf*16384, 8, 0, hhalf, row, l, oacc);
    BAR();                      // before next half overwrites hhalf
  }
  if (valid){
    #pragma unroll
    for(int mt=0;mt<8;++mt){
      float4 bb = *(const float4*)(b2p + mt*16 + g*4);
      f32x4 o;
      o[0] = xm[mt][0] + oacc[mt][0] + bb.x;
      o[1] = xm[mt][1] + oacc[mt][1] + bb.y;
      o[2] = xm[mt][2] + oacc[mt][2] + bb.z;
      o[3] = xm[mt][3] + oacc[mt][3] + bb.w;
      __builtin_nontemporal_store(o, (f32x4*)(xout + node*128 + mt*16 + g*4));
    }
  }
}

extern "C" void kernel_launch(void* const* d_in, const int* in_sizes, int n_in,
                              void* d_out, int out_size, void* d_ws, size_t ws_size,
                              hipStream_t stream) {
  (void)in_sizes; (void)n_in; (void)out_size; (void)ws_size;
  const float* xin = (const float*)d_in[0];
  const float* ein = (const float*)d_in[1];
  const float* Wq = (const float*)d_in[2];  const float* bq = (const float*)d_in[3];
  const float* Wk = (const float*)d_in[4];  const float* bk = (const float*)d_in[5];
  const float* Wv = (const float*)d_in[6];  const float* bv = (const float*)d_in[7];
  const float* We = (const float*)d_in[8];  const float* be = (const float*)d_in[9];
  const float* Wg = (const float*)d_in[10]; const float* bg = (const float*)d_in[11];
  const float* Wo = (const float*)d_in[12]; const float* bo = (const float*)d_in[13];
  const float* Woe= (const float*)d_in[14]; const float* boe= (const float*)d_in[15];
  const float* l1g= (const float*)d_in[16]; const float* l1b= (const float*)d_in[17];
  const float* l1eg=(const float*)d_in[18]; const float* l1eb=(const float*)d_in[19];
  const float* l2g= (const float*)d_in[20]; const float* l2b= (const float*)d_in[21];
  const float* W1 = (const float*)d_in[22]; const float* b1 = (const float*)d_in[23];
  const float* W2 = (const float*)d_in[24]; const float* b2 = (const float*)d_in[25];
  const int* eidx = (const int*)d_in[26];

  float* xout = (float*)d_out;
  float* eout = xout + (size_t)NN*128;

  // ws: esc [NE*8 f32] | gv [NE*64 u32] | qv,kv,vv [NN*64 u32] | xattnb [NN*64 u32]
  //     | cnt [NN] | elist [NN*CAP] | packed W (bf16)
  float* escp = (float*)d_ws;
  u32* gvp = (u32*)(escp + (size_t)NE*8);
  u32* qv = gvp + (size_t)NE*64;
  u32* kv = qv + (size_t)NN*64;
  u32* vv = kv + (size_t)NN*64;
  u32* xattnb = vv + (size_t)NN*64;
  int* cnt = (int*)(xattnb + (size_t)NN*64);
  int* elist = cnt + NN;
  u16* pw  = (u16*)(elist + (size_t)NN*CAP);
  u16* pWq = pw;            u16* pWk = pWq + 16384;  u16* pWv = pWk + 16384;
  u16* pWe = pWv + 16384;   u16* pWg = pWe + 16384;  u16* pWoe= pWg + 16384;
  u16* pWo = pWoe + 16384;  u16* pW1 = pWo + 16384;  u16* pW2 = pW1 + 32768;
  u16* pWeg = pW2 + 32768;
  (void)pWe; (void)pWg;

  hipMemsetAsync(cnt, 0, NN*sizeof(int), stream);
  k_prep<<<PACKB + (NE+255)/256, 256, 0, stream>>>(Wq,Wk,Wv,We,Wg,Woe,Wo,W1,W2, pw,
                                                   eidx, cnt, elist);

  k_qkv<<<(NN+63)/64, 256, 0, stream>>>(xin, l1g, l1b, pWq, bq, pWk, bk, pWv, bv, qv, kv, vv);
  k_edge<<<NE/64, 512, 0, stream>>>(ein, l1eg, l1eb, pWeg, bg, be, pWoe, boe,
                                    eidx, qv, kv, vv, gvp, escp, eout);
  k_agg<<<(NN+3)/4, 256, 0, stream>>>(gvp, escp, elist, cnt, xattnb);
  k_out<<<(NN+63)/64, 256, 0, stream>>>(xin, xattnb, pWo, bo, l2g, l2b,
                                        pW1, b1, pW2, b2, xout);
}